// Round 1
// baseline (384.062 us; speedup 1.0000x reference)
//
#include <hip/hip_runtime.h>
#include <hip/hip_bf16.h>
#include <math.h>

// Problem dims (fixed by the reference)
#define M_DIM 16384
#define N_DIM 2048
#define K_DIM 2048

// GEMM geometry: 256x256 tile, BK=64 int8, 8 waves (2M x 4N), 3-deep LDS ring
#define BM 256
#define BN 256
#define BK 64
#define NT (K_DIM / BK)          // 32 K-tiles
#define TILE_BYTES (BM * BK)     // 16 KiB per matrix per ring slot

typedef __attribute__((ext_vector_type(4))) int i32x4;    // MFMA i8 A/B (16 int8) and C/D
typedef __attribute__((ext_vector_type(8))) char char8;   // 8B int8 store

typedef __attribute__((address_space(1))) const unsigned char global_u8;
typedef __attribute__((address_space(3))) unsigned char lds_u8;

// ---------- pre-pass 1: per-row signed-pow + int8 quantize (unchanged, verified) ----------
__global__ __launch_bounds__(256) void quant_x_kernel(const float* __restrict__ x,
                                                      const float* __restrict__ alpha,
                                                      char* __restrict__ xq,
                                                      float* __restrict__ s_a) {
  __shared__ float wmax[4];
  const int row = blockIdx.x;
  const int tid = threadIdx.x;
  const size_t base = (size_t)row * K_DIM + tid * 8;
  const float a = alpha[0];
  const float4* xp = (const float4*)(x + base);
  float4 v0 = xp[0];
  float4 v1 = xp[1];
  float v[8] = {v0.x, v0.y, v0.z, v0.w, v1.x, v1.y, v1.z, v1.w};
  if (a == 0.5f) {  // uniform branch; setup uses a = 0.5 exactly
#pragma unroll
    for (int i = 0; i < 8; ++i) v[i] = copysignf(sqrtf(fabsf(v[i])), v[i]);
  } else {
#pragma unroll
    for (int i = 0; i < 8; ++i) v[i] = copysignf(powf(fabsf(v[i]), a), v[i]);
  }
  float m = 0.f;
#pragma unroll
  for (int i = 0; i < 8; ++i) m = fmaxf(m, fabsf(v[i]));
#pragma unroll
  for (int off = 32; off > 0; off >>= 1) m = fmaxf(m, __shfl_down(m, off));
  if ((tid & 63) == 0) wmax[tid >> 6] = m;
  __syncthreads();
  float rowmax = fmaxf(fmaxf(wmax[0], wmax[1]), fmaxf(wmax[2], wmax[3]));
  float inv, s;
  if (rowmax > 0.f) { inv = 127.0f / rowmax; s = rowmax * (1.0f / 127.0f); }
  else { inv = 0.f; s = 0.f; }
  char8 q;
#pragma unroll
  for (int i = 0; i < 8; ++i) {
    int qi = (int)__builtin_rintf(v[i] * inv);
    qi = qi > 127 ? 127 : (qi < -127 ? -127 : qi);
    q[i] = (char)qi;
  }
  *(char8*)(xq + base) = q;
  if (tid == 0) s_a[row] = s;
}

// ---------- pre-pass 2: codebook gather -> int8, per-tensor scale (unchanged) ----------
__global__ __launch_bounds__(256) void quant_w_kernel(const int* __restrict__ Wq,
                                                      const float* __restrict__ cent,
                                                      char* __restrict__ wq8,
                                                      float* __restrict__ s_w) {
  __shared__ char cb[16];
  const int tid = threadIdx.x;
  float cmax = 0.f;
#pragma unroll
  for (int j = 0; j < 16; ++j) cmax = fmaxf(cmax, fabsf(cent[j]));
  const float invw = 127.0f / cmax;
  if (tid < 16) cb[tid] = (char)__builtin_rintf(cent[tid] * invw);
  __syncthreads();
  const size_t base = ((size_t)blockIdx.x * 256u + tid) * 8u;
  const int4* qp = (const int4*)(Wq + base);
  int4 q0 = qp[0], q1 = qp[1];
  char8 r;
  r[0] = cb[q0.x]; r[1] = cb[q0.y]; r[2] = cb[q0.z]; r[3] = cb[q0.w];
  r[4] = cb[q1.x]; r[5] = cb[q1.y]; r[6] = cb[q1.z]; r[7] = cb[q1.w];
  *(char8*)(wq8 + base) = r;
  if (blockIdx.x == 0 && tid == 0) s_w[0] = cmax * (1.0f / 127.0f);
}

// ---------- GEMM: 256^2 tile, 2-phase/K-tile, 3-buffer ring, counted vmcnt ----------
// Schedule invariant (per wave, 4 global_load_lds per K-tile):
//   at start of tile t: tile t fully staged + barrier'd; tile t+1's 4 loads in flight.
//   during tile t: phase A stages A-halves of t+2, phase B stages B-halves of t+2.
//   tile-end: s_waitcnt vmcnt(4) retires t+1's loads, leaves t+2's in flight (T4).
// Ring slot (t+2)%3 == (t-1)%3 was last read in tile t-1 (before two barriers) -> no WAR race.
#define STAGE16(SRC, DST) \
  __builtin_amdgcn_global_load_lds((global_u8*)(SRC), (lds_u8*)(DST), 16, 0, 0)

#define MFMA4(mi, AF) \
  acc[mi][0] = __builtin_amdgcn_mfma_i32_16x16x64_i8(AF, b0, acc[mi][0], 0, 0, 0); \
  acc[mi][1] = __builtin_amdgcn_mfma_i32_16x16x64_i8(AF, b1, acc[mi][1], 0, 0, 0); \
  acc[mi][2] = __builtin_amdgcn_mfma_i32_16x16x64_i8(AF, b2, acc[mi][2], 0, 0, 0); \
  acc[mi][3] = __builtin_amdgcn_mfma_i32_16x16x64_i8(AF, b3, acc[mi][3], 0, 0, 0);

#define SBAR() __builtin_amdgcn_sched_barrier(0)
#define BLOCK_BARRIER() do { SBAR(); __builtin_amdgcn_s_barrier(); SBAR(); } while (0)

__global__ __launch_bounds__(512, 2) void gemm_i8_kernel(const unsigned char* __restrict__ A,
                                                         const unsigned char* __restrict__ B,
                                                         float* __restrict__ C,
                                                         const float* __restrict__ alpha,
                                                         const float* __restrict__ s_a,
                                                         const float* __restrict__ s_w) {
  __shared__ unsigned char As[3][TILE_BYTES];  // 48 KiB
  __shared__ unsigned char Bs[3][TILE_BYTES];  // 48 KiB

  const int tid  = threadIdx.x;
  const int wave = tid >> 6;     // 0..7
  const int lane = tid & 63;
  const int wm   = wave >> 2;    // 0..1  (M half of block tile)
  const int wn   = wave & 3;     // 0..3  (N quarter)
  const int r    = lane & 15;
  const int quad = lane >> 4;

  // bijective XCD chunk swizzle: 512 wgs, 8 XCDs, 64 contiguous per chunk; n-fastest
  const int bid = blockIdx.x;
  const int wg  = (bid & 7) * 64 + (bid >> 3);
  const int m0  = (wg >> 3) * BM;  // 64 m-tiles
  const int n0  = (wg & 7) * BN;   // 8  n-tiles

  // staging: 4 lanes/row (64B rows); source pre-swizzled cg ^= (row&3); LDS dest linear
  const int srow = tid >> 2;                  // 0..127 within a 128-row set
  const int scg  = (tid & 3) ^ (srow & 3);
  const unsigned char* aSrc = A + (size_t)(m0 + srow) * K_DIM + scg * 16;
  const unsigned char* bSrc = B + (size_t)(n0 + srow) * K_DIM + scg * 16;
  const int dst0 = (wave * 16) * BK;          // set 0: rows   0..127, wave-uniform base
  const int dst1 = (128 + wave * 16) * BK;    // set 1: rows 128..255

  // read-side swizzled fragment offsets (ds_read_b128; involution matches staging)
  const int swz  = ((quad ^ (r & 3)) << 4);
  const int aOff = (wm * 128 + r) * BK + swz;
  const int bOff = (wn * 64 + r) * BK + swz;

  i32x4 acc[8][4];
#pragma unroll
  for (int i = 0; i < 8; ++i)
#pragma unroll
    for (int j = 0; j < 4; ++j) acc[i][j] = i32x4{0, 0, 0, 0};

  // ---- prologue: stage tile 0 (buf0) and tile 1 (buf1) ----
  STAGE16(aSrc,                            &As[0][dst0]);
  STAGE16(aSrc + (size_t)128 * K_DIM,      &As[0][dst1]);
  STAGE16(bSrc,                            &Bs[0][dst0]);
  STAGE16(bSrc + (size_t)128 * K_DIM,      &Bs[0][dst1]);
  STAGE16(aSrc + BK,                       &As[1][dst0]);
  STAGE16(aSrc + (size_t)128 * K_DIM + BK, &As[1][dst1]);
  STAGE16(bSrc + BK,                       &Bs[1][dst0]);
  STAGE16(bSrc + (size_t)128 * K_DIM + BK, &Bs[1][dst1]);
  asm volatile("s_waitcnt vmcnt(4)" ::: "memory");  // tile 0 landed; tile 1 in flight
  BLOCK_BARRIER();

  int buf = 0, pbuf = 2;
  for (int t = 0; t < NT; ++t) {
    const unsigned ap = (unsigned)(size_t)(lds_u8*)&As[buf][aOff];
    const unsigned bp = (unsigned)(size_t)(lds_u8*)&Bs[buf][bOff];
    const bool pre = (t < NT - 2);
    const size_t kpre = (size_t)(t + 2) * BK;

    // ================= phase A: acc rows 0..63 of wave tile =================
    i32x4 a0, a1, a2, a3, b0, b1, b2, b3;
    asm volatile("ds_read_b128 %0, %4 offset:0\n\t"
                 "ds_read_b128 %1, %4 offset:1024\n\t"
                 "ds_read_b128 %2, %4 offset:2048\n\t"
                 "ds_read_b128 %3, %4 offset:3072"
                 : "=&v"(a0), "=&v"(a1), "=&v"(a2), "=&v"(a3)
                 : "v"(ap));
    asm volatile("ds_read_b128 %0, %4 offset:0\n\t"
                 "ds_read_b128 %1, %4 offset:1024\n\t"
                 "ds_read_b128 %2, %4 offset:2048\n\t"
                 "ds_read_b128 %3, %4 offset:3072"
                 : "=&v"(b0), "=&v"(b1), "=&v"(b2), "=&v"(b3)
                 : "v"(bp));
    if (pre) {  // stage A halves of tile t+2
      STAGE16(aSrc + kpre,                       &As[pbuf][dst0]);
      STAGE16(aSrc + (size_t)128 * K_DIM + kpre, &As[pbuf][dst1]);
    }
    BLOCK_BARRIER();
    asm volatile("s_waitcnt lgkmcnt(0)" ::: "memory");
    SBAR();  // rule #18: pin MFMAs below the wait
    __builtin_amdgcn_s_setprio(1);
    MFMA4(0, a0); MFMA4(1, a1); MFMA4(2, a2); MFMA4(3, a3);
    __builtin_amdgcn_s_setprio(0);
    BLOCK_BARRIER();

    // ================= phase B: acc rows 64..127 (B frags reused) =================
    i32x4 a4, a5, a6, a7;
    asm volatile("ds_read_b128 %0, %4 offset:4096\n\t"
                 "ds_read_b128 %1, %4 offset:5120\n\t"
                 "ds_read_b128 %2, %4 offset:6144\n\t"
                 "ds_read_b128 %3, %4 offset:7168"
                 : "=&v"(a4), "=&v"(a5), "=&v"(a6), "=&v"(a7)
                 : "v"(ap));
    if (pre) {  // stage B halves of tile t+2
      STAGE16(bSrc + kpre,                       &Bs[pbuf][dst0]);
      STAGE16(bSrc + (size_t)128 * K_DIM + kpre, &Bs[pbuf][dst1]);
    }
    BLOCK_BARRIER();
    asm volatile("s_waitcnt lgkmcnt(0)" ::: "memory");
    SBAR();
    __builtin_amdgcn_s_setprio(1);
    MFMA4(4, a4); MFMA4(5, a5); MFMA4(6, a6); MFMA4(7, a7);
    __builtin_amdgcn_s_setprio(0);
    SBAR();
    // tile boundary: retire tile t+1's 4 loads; keep t+2's 4 in flight (never 0 mid-loop)
    if (pre) { asm volatile("s_waitcnt vmcnt(4)" ::: "memory"); }
    else     { asm volatile("s_waitcnt vmcnt(0)" ::: "memory"); }
    BLOCK_BARRIER();

    buf  = (buf == 2) ? 0 : buf + 1;
    pbuf = (pbuf == 2) ? 0 : pbuf + 1;
  }

  // epilogue: t = s_a[row]*s_w*idot; out = sign(t)*|t|^(1/a); a==0.5 -> t*|t|
  const float a = alpha[0];
  const bool simple = (a == 0.5f);
  const float inv_a = 1.0f / a;
  const float sw = s_w[0];
#pragma unroll
  for (int mf = 0; mf < 8; ++mf) {
    const int gmb = m0 + wm * 128 + mf * 16 + quad * 4;
    float sa[4];
#pragma unroll
    for (int v = 0; v < 4; ++v) sa[v] = s_a[gmb + v] * sw;
#pragma unroll
    for (int nf = 0; nf < 4; ++nf) {
      const int gn = n0 + wn * 64 + nf * 16 + r;
      float* cp = C + (size_t)gmb * N_DIM + gn;
#pragma unroll
      for (int v = 0; v < 4; ++v) {
        float tv = (float)acc[mf][nf][v] * sa[v];
        cp[(size_t)v * N_DIM] = simple ? tv * fabsf(tv)
                                       : copysignf(powf(fabsf(tv), inv_a), tv);
      }
    }
  }
}

extern "C" void kernel_launch(void* const* d_in, const int* in_sizes, int n_in,
                              void* d_out, int out_size, void* d_ws, size_t ws_size,
                              hipStream_t stream) {
  const float* x     = (const float*)d_in[0];  // [16384, 2048] fp32
  const float* cent  = (const float*)d_in[1];  // [16] fp32
  const float* alpha = (const float*)d_in[2];  // [1] fp32
  const int*   Wq    = (const int*)d_in[3];    // [2048, 2048] int32
  float* out = (float*)d_out;                  // [16384, 2048] fp32

  // ws layout: xq int8 [M][K] (32 MiB) | wq8 int8 [N][K] (4 MiB) | s_a [M] f32 | s_w [1] f32
  char*  xq  = (char*)d_ws;
  char*  wq8 = xq + (size_t)M_DIM * K_DIM;
  float* s_a = (float*)(wq8 + (size_t)N_DIM * K_DIM);
  float* s_w = s_a + M_DIM;

  quant_x_kernel<<<M_DIM, 256, 0, stream>>>(x, alpha, xq, s_a);
  quant_w_kernel<<<(N_DIM * (size_t)K_DIM) / (256 * 8), 256, 0, stream>>>(Wq, cent, wq8, s_w);

  dim3 grid((M_DIM / BM) * (N_DIM / BN));  // 512 blocks, 1 per CU, 2 rounds
  gemm_i8_kernel<<<grid, 512, 0, stream>>>((const unsigned char*)xq, (const unsigned char*)wq8,
                                           out, alpha, s_a, s_w);
}

// Round 2
// 341.067 us; speedup vs baseline: 1.1261x; 1.1261x over previous
//
#include <hip/hip_runtime.h>
#include <math.h>

// Problem dims (fixed by the reference)
#define M_DIM 16384
#define N_DIM 2048
#define K_DIM 2048
#define BM 128
#define BN 128
#define BK 64            // K-tile in BYTES (int8) == one mfma_i32_16x16x64_i8 k-step
#define NT (K_DIM / BK)  // 32 K-tiles

typedef __attribute__((ext_vector_type(4))) int i32x4;    // MFMA i8 A/B (16 int8) and C/D
typedef __attribute__((ext_vector_type(8))) char char8;   // 8B int8 store
typedef __attribute__((ext_vector_type(4))) char char4v;  // 4B int8 store

typedef __attribute__((address_space(1))) const unsigned char global_u8;
typedef __attribute__((address_space(3))) unsigned char lds_u8;

// ---------- pre-pass 1: per-row signed-pow + int8 quantize ----------
// ONE WAVE per row (no cross-wave reduce, no __syncthreads): 4 rows / 256-thread block.
// Math identical to the verified version: v=sign(x)*|x|^a; s=rowmax/127; q=rint(v/s) clamped.
__global__ __launch_bounds__(256) void quant_x_kernel(const float* __restrict__ x,
                                                      const float* __restrict__ alpha,
                                                      char* __restrict__ xq,
                                                      float* __restrict__ s_a) {
  const int wave = threadIdx.x >> 6;
  const int lane = threadIdx.x & 63;
  const int row  = blockIdx.x * 4 + wave;
  const size_t rb = (size_t)row * K_DIM;
  const float a = alpha[0];
  const float4* xp = (const float4*)(x + rb);

  float v[32];
  float m = 0.f;
  if (a == 0.5f) {  // uniform branch; setup uses a = 0.5 exactly
#pragma unroll
    for (int it = 0; it < 8; ++it) {
      float4 t = xp[it * 64 + lane];
      float e[4] = {t.x, t.y, t.z, t.w};
#pragma unroll
      for (int j = 0; j < 4; ++j) {
        float w = copysignf(sqrtf(fabsf(e[j])), e[j]);
        v[it * 4 + j] = w;
        m = fmaxf(m, fabsf(w));
      }
    }
  } else {
#pragma unroll
    for (int it = 0; it < 8; ++it) {
      float4 t = xp[it * 64 + lane];
      float e[4] = {t.x, t.y, t.z, t.w};
#pragma unroll
      for (int j = 0; j < 4; ++j) {
        float w = copysignf(powf(fabsf(e[j]), a), e[j]);
        v[it * 4 + j] = w;
        m = fmaxf(m, fabsf(w));
      }
    }
  }
  // wave64 max reduce
#pragma unroll
  for (int off = 32; off > 0; off >>= 1) m = fmaxf(m, __shfl_xor(m, off));
  float inv, s;
  if (m > 0.f) { inv = 127.0f / m; s = m * (1.0f / 127.0f); }
  else { inv = 0.f; s = 0.f; }

  char* out = xq + rb;
#pragma unroll
  for (int it = 0; it < 8; ++it) {
    char4v q;
#pragma unroll
    for (int j = 0; j < 4; ++j) {
      int qi = (int)__builtin_rintf(v[it * 4 + j] * inv);
      qi = qi > 127 ? 127 : (qi < -127 ? -127 : qi);
      q[j] = (char)qi;
    }
    *(char4v*)(out + (size_t)(it * 64 + lane) * 4) = q;
  }
  if (lane == 0) s_a[row] = s;
}

// ---------- pre-pass 2: codebook gather -> int8, per-tensor scale (unchanged) ----------
__global__ __launch_bounds__(256) void quant_w_kernel(const int* __restrict__ Wq,
                                                      const float* __restrict__ cent,
                                                      char* __restrict__ wq8,
                                                      float* __restrict__ s_w) {
  __shared__ char cb[16];
  const int tid = threadIdx.x;
  float cmax = 0.f;
#pragma unroll
  for (int j = 0; j < 16; ++j) cmax = fmaxf(cmax, fabsf(cent[j]));
  const float invw = 127.0f / cmax;
  if (tid < 16) cb[tid] = (char)__builtin_rintf(cent[tid] * invw);
  __syncthreads();
  const size_t base = ((size_t)blockIdx.x * 256u + tid) * 8u;
  const int4* qp = (const int4*)(Wq + base);
  int4 q0 = qp[0], q1 = qp[1];
  char8 r;
  r[0] = cb[q0.x]; r[1] = cb[q0.y]; r[2] = cb[q0.z]; r[3] = cb[q0.w];
  r[4] = cb[q1.x]; r[5] = cb[q1.y]; r[6] = cb[q1.z]; r[7] = cb[q1.w];
  *(char8*)(wq8 + base) = r;
  if (blockIdx.x == 0 && tid == 0) s_w[0] = cmax * (1.0f / 127.0f);
}

// ---------- GEMM: round-0 geometry + minimum-2-phase pipeline (catalog T3-min) ----------
// 128x128 tile, 4 waves, BK=64 double-buffered (32 KiB LDS, same as round 0).
// Per tile: STAGE(t+1 -> buf^1) issued FIRST, then ds_read(buf) + 16 MFMA, then ONE
// __syncthreads() (its vmcnt(0)+lgkmcnt(0) drain is exactly the intended tile-end drain).
// Same barrier density and MFMA-per-barrier as round 0, but staging overlaps compute.
#define STAGE16(SRC, DST) \
  __builtin_amdgcn_global_load_lds((global_u8*)(SRC), (lds_u8*)(DST), 16, 0, 0)

__global__ __launch_bounds__(256) void gemm_i8_kernel(const unsigned char* __restrict__ A,
                                                      const unsigned char* __restrict__ B,
                                                      float* __restrict__ C,
                                                      const float* __restrict__ alpha,
                                                      const float* __restrict__ s_a,
                                                      const float* __restrict__ s_w) {
  __shared__ unsigned char As[2][BM * BK];  // 2 x 8 KiB
  __shared__ unsigned char Bs[2][BN * BK];  // 2 x 8 KiB

  const int tid  = threadIdx.x;
  const int wave = tid >> 6;
  const int lane = tid & 63;
  const int wm   = wave >> 1;
  const int wn   = wave & 1;
  const int r    = lane & 15;
  const int quad = lane >> 4;

  // 16x16 super-tile block swizzle (L2 locality) — unchanged from round 0
  const int bid    = blockIdx.x;  // 0..2047
  const int st     = bid >> 8;
  const int within = bid & 255;
  const int m0 = (st * 16 + (within & 15)) * BM;
  const int n0 = (within >> 4) * BN;

  // staging: 4 lanes/row (64B rows). Source pre-swizzled slot^(row&3); LDS dest linear.
  const int srow = tid >> 2;                 // 0..63 within a 64-row chunk
  const int scg  = (tid & 3) ^ (srow & 3);   // XOR swizzle (involution)
  const unsigned char* aSrc = A + (size_t)(m0 + srow) * K_DIM + scg * 16;
  const unsigned char* bSrc = B + (size_t)(n0 + srow) * K_DIM + scg * 16;
  const int dstOff = wave * 1024;            // wave-uniform base; HW adds lane*16

  // read-side swizzled fragment offsets (conflict-free: 8 lanes/bank-row hit 8 slots)
  const int swz  = (quad ^ (r & 3)) << 4;
  const int aOff = (wm * 64 + r) * BK + swz;
  const int bOff = (wn * 64 + r) * BK + swz;

  i32x4 acc[4][4];
#pragma unroll
  for (int i = 0; i < 4; ++i)
#pragma unroll
    for (int j = 0; j < 4; ++j) acc[i][j] = i32x4{0, 0, 0, 0};

#define STAGE_TILE(BUF, K0)                                                     \
  do {                                                                          \
    STAGE16(aSrc + (K0),                         &As[BUF][dstOff]);             \
    STAGE16(aSrc + (size_t)64 * K_DIM + (K0),    &As[BUF][4096 + dstOff]);      \
    STAGE16(bSrc + (K0),                         &Bs[BUF][dstOff]);             \
    STAGE16(bSrc + (size_t)64 * K_DIM + (K0),    &Bs[BUF][4096 + dstOff]);      \
  } while (0)

  // prologue: stage tile 0
  STAGE_TILE(0, 0);
  __syncthreads();

  for (int t = 0; t < NT; ++t) {
    const int buf = t & 1;
    if (t + 1 < NT) STAGE_TILE(buf ^ 1, (size_t)(t + 1) * BK);  // overlap with compute

    const unsigned ap = (unsigned)(size_t)(lds_u8*)&As[buf][aOff];
    const unsigned bp = (unsigned)(size_t)(lds_u8*)&Bs[buf][bOff];
    i32x4 a0, a1, a2, a3, b0, b1, b2, b3;
    asm volatile("ds_read_b128 %0, %4 offset:0\n\t"
                 "ds_read_b128 %1, %4 offset:1024\n\t"
                 "ds_read_b128 %2, %4 offset:2048\n\t"
                 "ds_read_b128 %3, %4 offset:3072"
                 : "=&v"(a0), "=&v"(a1), "=&v"(a2), "=&v"(a3)
                 : "v"(ap));
    asm volatile("ds_read_b128 %0, %4 offset:0\n\t"
                 "ds_read_b128 %1, %4 offset:1024\n\t"
                 "ds_read_b128 %2, %4 offset:2048\n\t"
                 "ds_read_b128 %3, %4 offset:3072"
                 : "=&v"(b0), "=&v"(b1), "=&v"(b2), "=&v"(b3)
                 : "v"(bp));
    asm volatile("s_waitcnt lgkmcnt(0)" ::: "memory");
    __builtin_amdgcn_sched_barrier(0);  // rule #18: pin MFMAs below the wait

    acc[0][0] = __builtin_amdgcn_mfma_i32_16x16x64_i8(a0, b0, acc[0][0], 0, 0, 0);
    acc[0][1] = __builtin_amdgcn_mfma_i32_16x16x64_i8(a0, b1, acc[0][1], 0, 0, 0);
    acc[0][2] = __builtin_amdgcn_mfma_i32_16x16x64_i8(a0, b2, acc[0][2], 0, 0, 0);
    acc[0][3] = __builtin_amdgcn_mfma_i32_16x16x64_i8(a0, b3, acc[0][3], 0, 0, 0);
    acc[1][0] = __builtin_amdgcn_mfma_i32_16x16x64_i8(a1, b0, acc[1][0], 0, 0, 0);
    acc[1][1] = __builtin_amdgcn_mfma_i32_16x16x64_i8(a1, b1, acc[1][1], 0, 0, 0);
    acc[1][2] = __builtin_amdgcn_mfma_i32_16x16x64_i8(a1, b2, acc[1][2], 0, 0, 0);
    acc[1][3] = __builtin_amdgcn_mfma_i32_16x16x64_i8(a1, b3, acc[1][3], 0, 0, 0);
    acc[2][0] = __builtin_amdgcn_mfma_i32_16x16x64_i8(a2, b0, acc[2][0], 0, 0, 0);
    acc[2][1] = __builtin_amdgcn_mfma_i32_16x16x64_i8(a2, b1, acc[2][1], 0, 0, 0);
    acc[2][2] = __builtin_amdgcn_mfma_i32_16x16x64_i8(a2, b2, acc[2][2], 0, 0, 0);
    acc[2][3] = __builtin_amdgcn_mfma_i32_16x16x64_i8(a2, b3, acc[2][3], 0, 0, 0);
    acc[3][0] = __builtin_amdgcn_mfma_i32_16x16x64_i8(a3, b0, acc[3][0], 0, 0, 0);
    acc[3][1] = __builtin_amdgcn_mfma_i32_16x16x64_i8(a3, b1, acc[3][1], 0, 0, 0);
    acc[3][2] = __builtin_amdgcn_mfma_i32_16x16x64_i8(a3, b2, acc[3][2], 0, 0, 0);
    acc[3][3] = __builtin_amdgcn_mfma_i32_16x16x64_i8(a3, b3, acc[3][3], 0, 0, 0);

    __syncthreads();  // ONE drain+barrier per tile (vmcnt(0) lgkmcnt(0) + s_barrier)
  }

  // epilogue: t = s_a[row]*s_w*idot; out = sign(t)*|t|^(1/a); a==0.5 -> t*|t|
  const float a = alpha[0];
  const bool simple = (a == 0.5f);
  const float inv_a = 1.0f / a;
  const float sw = s_w[0];
#pragma unroll
  for (int mf = 0; mf < 4; ++mf) {
    const int gmb = m0 + wm * 64 + mf * 16 + quad * 4;
    float sa[4];
#pragma unroll
    for (int v = 0; v < 4; ++v) sa[v] = s_a[gmb + v] * sw;
#pragma unroll
    for (int nf = 0; nf < 4; ++nf) {
      const int gn = n0 + wn * 64 + nf * 16 + r;
      float* cp = C + (size_t)gmb * N_DIM + gn;
#pragma unroll
      for (int v = 0; v < 4; ++v) {
        float tv = (float)acc[mf][nf][v] * sa[v];
        cp[(size_t)v * N_DIM] = simple ? tv * fabsf(tv)
                                       : copysignf(powf(fabsf(tv), inv_a), tv);
      }
    }
  }
}

extern "C" void kernel_launch(void* const* d_in, const int* in_sizes, int n_in,
                              void* d_out, int out_size, void* d_ws, size_t ws_size,
                              hipStream_t stream) {
  const float* x     = (const float*)d_in[0];  // [16384, 2048] fp32
  const float* cent  = (const float*)d_in[1];  // [16] fp32
  const float* alpha = (const float*)d_in[2];  // [1] fp32
  const int*   Wq    = (const int*)d_in[3];    // [2048, 2048] int32
  float* out = (float*)d_out;                  // [16384, 2048] fp32

  // ws layout: xq int8 [M][K] (32 MiB) | wq8 int8 [N][K] (4 MiB) | s_a [M] f32 | s_w [1] f32
  char*  xq  = (char*)d_ws;
  char*  wq8 = xq + (size_t)M_DIM * K_DIM;
  float* s_a = (float*)(wq8 + (size_t)N_DIM * K_DIM);
  float* s_w = s_a + M_DIM;

  quant_x_kernel<<<M_DIM / 4, 256, 0, stream>>>(x, alpha, xq, s_a);
  quant_w_kernel<<<(N_DIM * (size_t)K_DIM) / (256 * 8), 256, 0, stream>>>(Wq, cent, wq8, s_w);

  dim3 grid((M_DIM / BM) * (N_DIM / BN));  // 2048 blocks
  gemm_i8_kernel<<<grid, 256, 0, stream>>>((const unsigned char*)xq, (const unsigned char*)wq8,
                                           out, alpha, s_a, s_w);
}

// Round 3
// 331.599 us; speedup vs baseline: 1.1582x; 1.0286x over previous
//
#include <hip/hip_runtime.h>
#include <math.h>

// Problem dims (fixed by the reference)
#define M_DIM 16384
#define N_DIM 2048
#define K_DIM 2048
#define BM 128
#define BN 128
#define BK 64            // K-tile in BYTES (int8) == one mfma_i32_16x16x64_i8 k-step
#define NT (K_DIM / BK)  // 32 K-tiles

typedef __attribute__((ext_vector_type(4))) int i32x4;    // MFMA i8 A/B (16 int8) and C/D
typedef __attribute__((ext_vector_type(8))) char char8;   // 8B int8 store
typedef __attribute__((ext_vector_type(4))) char char4v;  // 4B int8 store

typedef __attribute__((address_space(1))) const unsigned char global_u8;
typedef __attribute__((address_space(3))) unsigned char lds_u8;

// ---------- pre-pass 1: per-row signed-pow + int8 quantize (one wave per row) ----------
__global__ __launch_bounds__(256) void quant_x_kernel(const float* __restrict__ x,
                                                      const float* __restrict__ alpha,
                                                      char* __restrict__ xq,
                                                      float* __restrict__ s_a) {
  const int wave = threadIdx.x >> 6;
  const int lane = threadIdx.x & 63;
  const int row  = blockIdx.x * 4 + wave;
  const size_t rb = (size_t)row * K_DIM;
  const float a = alpha[0];
  const float4* xp = (const float4*)(x + rb);

  float v[32];
  float m = 0.f;
  if (a == 0.5f) {  // uniform branch; setup uses a = 0.5 exactly
#pragma unroll
    for (int it = 0; it < 8; ++it) {
      float4 t = xp[it * 64 + lane];
      float e[4] = {t.x, t.y, t.z, t.w};
#pragma unroll
      for (int j = 0; j < 4; ++j) {
        float w = copysignf(sqrtf(fabsf(e[j])), e[j]);
        v[it * 4 + j] = w;
        m = fmaxf(m, fabsf(w));
      }
    }
  } else {
#pragma unroll
    for (int it = 0; it < 8; ++it) {
      float4 t = xp[it * 64 + lane];
      float e[4] = {t.x, t.y, t.z, t.w};
#pragma unroll
      for (int j = 0; j < 4; ++j) {
        float w = copysignf(powf(fabsf(e[j]), a), e[j]);
        v[it * 4 + j] = w;
        m = fmaxf(m, fabsf(w));
      }
    }
  }
#pragma unroll
  for (int off = 32; off > 0; off >>= 1) m = fmaxf(m, __shfl_xor(m, off));
  float inv, s;
  if (m > 0.f) { inv = 127.0f / m; s = m * (1.0f / 127.0f); }
  else { inv = 0.f; s = 0.f; }

  char* out = xq + rb;
#pragma unroll
  for (int it = 0; it < 8; ++it) {
    char4v q;
#pragma unroll
    for (int j = 0; j < 4; ++j) {
      int qi = (int)__builtin_rintf(v[it * 4 + j] * inv);
      qi = qi > 127 ? 127 : (qi < -127 ? -127 : qi);
      q[j] = (char)qi;
    }
    *(char4v*)(out + (size_t)(it * 64 + lane) * 4) = q;
  }
  if (lane == 0) s_a[row] = s;
}

// ---------- pre-pass 2: codebook gather -> int8, per-tensor scale (unchanged) ----------
__global__ __launch_bounds__(256) void quant_w_kernel(const int* __restrict__ Wq,
                                                      const float* __restrict__ cent,
                                                      char* __restrict__ wq8,
                                                      float* __restrict__ s_w) {
  __shared__ char cb[16];
  const int tid = threadIdx.x;
  float cmax = 0.f;
#pragma unroll
  for (int j = 0; j < 16; ++j) cmax = fmaxf(cmax, fabsf(cent[j]));
  const float invw = 127.0f / cmax;
  if (tid < 16) cb[tid] = (char)__builtin_rintf(cent[tid] * invw);
  __syncthreads();
  const size_t base = ((size_t)blockIdx.x * 256u + tid) * 8u;
  const int4* qp = (const int4*)(Wq + base);
  int4 q0 = qp[0], q1 = qp[1];
  char8 r;
  r[0] = cb[q0.x]; r[1] = cb[q0.y]; r[2] = cb[q0.z]; r[3] = cb[q0.w];
  r[4] = cb[q1.x]; r[5] = cb[q1.y]; r[6] = cb[q1.z]; r[7] = cb[q1.w];
  *(char8*)(wq8 + base) = r;
  if (blockIdx.x == 0 && tid == 0) s_w[0] = cmax * (1.0f / 127.0f);
}

// ---------- GEMM: 128^2, 4 waves, 3-buffer ring, counted vmcnt (T3+T4) ----------
// Swizzle (both-sides involution, conflict-free): phys 16B-group = logical ^ ((row>>1)&3).
//   Read check: bank-group = (4*(row&1) + quad^((row>>1)&3)) & 7 covers all 8 groups
//   exactly once over any 8 consecutive lanes (quad fixed, row=r..r+7).
// Pipeline invariant (4 global_load_lds per wave per tile):
//   iter t: issue stage(t+2) into slot (t+2)%3; compute slot t%3;
//   tile end: s_waitcnt vmcnt(4) retires t+1's loads, keeps t+2's in flight; s_barrier.
//   WAR safe: slot (t+2)%3 == (t-1)%3 was last ds_read in iter t-1, and every wave did
//   lgkmcnt(0) before reaching iter t-1's end barrier, which precedes iter t's stage issue.
#define STAGE16(SRC, DST) \
  __builtin_amdgcn_global_load_lds((global_u8*)(SRC), (lds_u8*)(DST), 16, 0, 0)
#define SBAR() __builtin_amdgcn_sched_barrier(0)

__global__ __launch_bounds__(256) void gemm_i8_kernel(const unsigned char* __restrict__ A,
                                                      const unsigned char* __restrict__ B,
                                                      float* __restrict__ C,
                                                      const float* __restrict__ alpha,
                                                      const float* __restrict__ s_a,
                                                      const float* __restrict__ s_w) {
  __shared__ unsigned char As[3][BM * BK];  // 3 x 8 KiB
  __shared__ unsigned char Bs[3][BN * BK];  // 3 x 8 KiB

  const int tid  = threadIdx.x;
  const int wave = tid >> 6;
  const int lane = tid & 63;
  const int wm   = wave >> 1;
  const int wn   = wave & 1;
  const int r    = lane & 15;
  const int quad = lane >> 4;

  // 16x16 super-tile block swizzle (L2 locality) — unchanged
  const int bid    = blockIdx.x;  // 0..2047
  const int st     = bid >> 8;
  const int within = bid & 255;
  const int m0 = (st * 16 + (within & 15)) * BM;
  const int n0 = (within >> 4) * BN;

  // staging: 4 lanes/row (64B rows). Source pre-swizzled group^( (row>>1)&3 ); dest linear.
  const int srow = tid >> 2;                       // 0..63
  const int scg  = (tid & 3) ^ ((srow >> 1) & 3);  // involution (row-paired)
  const unsigned char* aSrc = A + (size_t)(m0 + srow) * K_DIM + scg * 16;
  const unsigned char* bSrc = B + (size_t)(n0 + srow) * K_DIM + scg * 16;
  const int dstOff = wave * 1024;                  // wave-uniform base; HW adds lane*16

  // read-side swizzled fragment offsets (matching involution)
  const int swz  = (quad ^ ((r >> 1) & 3)) << 4;
  const int aOff = (wm * 64 + r) * BK + swz;
  const int bOff = (wn * 64 + r) * BK + swz;

  i32x4 acc[4][4];
#pragma unroll
  for (int i = 0; i < 4; ++i)
#pragma unroll
    for (int j = 0; j < 4; ++j) acc[i][j] = i32x4{0, 0, 0, 0};

#define STAGE_TILE(SLOT, K0)                                                    \
  do {                                                                          \
    STAGE16(aSrc + (K0),                      &As[SLOT][dstOff]);               \
    STAGE16(aSrc + (size_t)64 * K_DIM + (K0), &As[SLOT][4096 + dstOff]);        \
    STAGE16(bSrc + (K0),                      &Bs[SLOT][dstOff]);               \
    STAGE16(bSrc + (size_t)64 * K_DIM + (K0), &Bs[SLOT][4096 + dstOff]);        \
  } while (0)

  // prologue: stage tiles 0 and 1; wait for tile 0 only (tile 1 stays in flight)
  STAGE_TILE(0, 0);
  STAGE_TILE(1, BK);
  asm volatile("s_waitcnt vmcnt(4)" ::: "memory");
  SBAR(); __builtin_amdgcn_s_barrier(); SBAR();

  int buf = 0, pbuf = 2;
  for (int t = 0; t < NT; ++t) {
    if (t + 2 < NT) STAGE_TILE(pbuf, (size_t)(t + 2) * BK);

    const unsigned ap = (unsigned)(size_t)(lds_u8*)&As[buf][aOff];
    const unsigned bp = (unsigned)(size_t)(lds_u8*)&Bs[buf][bOff];
    i32x4 a0, a1, a2, a3, b0, b1, b2, b3;
    asm volatile("ds_read_b128 %0, %4 offset:0\n\t"
                 "ds_read_b128 %1, %4 offset:1024\n\t"
                 "ds_read_b128 %2, %4 offset:2048\n\t"
                 "ds_read_b128 %3, %4 offset:3072"
                 : "=&v"(a0), "=&v"(a1), "=&v"(a2), "=&v"(a3)
                 : "v"(ap));
    asm volatile("ds_read_b128 %0, %4 offset:0\n\t"
                 "ds_read_b128 %1, %4 offset:1024\n\t"
                 "ds_read_b128 %2, %4 offset:2048\n\t"
                 "ds_read_b128 %3, %4 offset:3072"
                 : "=&v"(b0), "=&v"(b1), "=&v"(b2), "=&v"(b3)
                 : "v"(bp));
    asm volatile("s_waitcnt lgkmcnt(0)" ::: "memory");
    SBAR();  // rule #18: pin MFMAs below the wait

    acc[0][0] = __builtin_amdgcn_mfma_i32_16x16x64_i8(a0, b0, acc[0][0], 0, 0, 0);
    acc[0][1] = __builtin_amdgcn_mfma_i32_16x16x64_i8(a0, b1, acc[0][1], 0, 0, 0);
    acc[0][2] = __builtin_amdgcn_mfma_i32_16x16x64_i8(a0, b2, acc[0][2], 0, 0, 0);
    acc[0][3] = __builtin_amdgcn_mfma_i32_16x16x64_i8(a0, b3, acc[0][3], 0, 0, 0);
    acc[1][0] = __builtin_amdgcn_mfma_i32_16x16x64_i8(a1, b0, acc[1][0], 0, 0, 0);
    acc[1][1] = __builtin_amdgcn_mfma_i32_16x16x64_i8(a1, b1, acc[1][1], 0, 0, 0);
    acc[1][2] = __builtin_amdgcn_mfma_i32_16x16x64_i8(a1, b2, acc[1][2], 0, 0, 0);
    acc[1][3] = __builtin_amdgcn_mfma_i32_16x16x64_i8(a1, b3, acc[1][3], 0, 0, 0);
    acc[2][0] = __builtin_amdgcn_mfma_i32_16x16x64_i8(a2, b0, acc[2][0], 0, 0, 0);
    acc[2][1] = __builtin_amdgcn_mfma_i32_16x16x64_i8(a2, b1, acc[2][1], 0, 0, 0);
    acc[2][2] = __builtin_amdgcn_mfma_i32_16x16x64_i8(a2, b2, acc[2][2], 0, 0, 0);
    acc[2][3] = __builtin_amdgcn_mfma_i32_16x16x64_i8(a2, b3, acc[2][3], 0, 0, 0);
    acc[3][0] = __builtin_amdgcn_mfma_i32_16x16x64_i8(a3, b0, acc[3][0], 0, 0, 0);
    acc[3][1] = __builtin_amdgcn_mfma_i32_16x16x64_i8(a3, b1, acc[3][1], 0, 0, 0);
    acc[3][2] = __builtin_amdgcn_mfma_i32_16x16x64_i8(a3, b2, acc[3][2], 0, 0, 0);
    acc[3][3] = __builtin_amdgcn_mfma_i32_16x16x64_i8(a3, b3, acc[3][3], 0, 0, 0);

    // tile end: retire t+1's loads only; t+2's stay in flight across the barrier (T4)
    SBAR();
    if (t < NT - 2) { asm volatile("s_waitcnt vmcnt(4)" ::: "memory"); }
    else            { asm volatile("s_waitcnt vmcnt(0)" ::: "memory"); }
    SBAR(); __builtin_amdgcn_s_barrier(); SBAR();

    buf  = (buf == 2) ? 0 : buf + 1;
    pbuf = (pbuf == 2) ? 0 : pbuf + 1;
  }

  // epilogue: t = s_a[row]*s_w*idot; out = sign(t)*|t|^(1/a); a==0.5 -> t*|t|
  const float a = alpha[0];
  const bool simple = (a == 0.5f);
  const float inv_a = 1.0f / a;
  const float sw = s_w[0];
#pragma unroll
  for (int mf = 0; mf < 4; ++mf) {
    const int gmb = m0 + wm * 64 + mf * 16 + quad * 4;
    float sa[4];
#pragma unroll
    for (int v = 0; v < 4; ++v) sa[v] = s_a[gmb + v] * sw;
#pragma unroll
    for (int nf = 0; nf < 4; ++nf) {
      const int gn = n0 + wn * 64 + nf * 16 + r;
      float* cp = C + (size_t)gmb * N_DIM + gn;
#pragma unroll
      for (int v = 0; v < 4; ++v) {
        float tv = (float)acc[mf][nf][v] * sa[v];
        cp[(size_t)v * N_DIM] = simple ? tv * fabsf(tv)
                                       : copysignf(powf(fabsf(tv), inv_a), tv);
      }
    }
  }
}

extern "C" void kernel_launch(void* const* d_in, const int* in_sizes, int n_in,
                              void* d_out, int out_size, void* d_ws, size_t ws_size,
                              hipStream_t stream) {
  const float* x     = (const float*)d_in[0];  // [16384, 2048] fp32
  const float* cent  = (const float*)d_in[1];  // [16] fp32
  const float* alpha = (const float*)d_in[2];  // [1] fp32
  const int*   Wq    = (const int*)d_in[3];    // [2048, 2048] int32
  float* out = (float*)d_out;                  // [16384, 2048] fp32

  // ws layout: xq int8 [M][K] (32 MiB) | wq8 int8 [N][K] (4 MiB) | s_a [M] f32 | s_w [1] f32
  char*  xq  = (char*)d_ws;
  char*  wq8 = xq + (size_t)M_DIM * K_DIM;
  float* s_a = (float*)(wq8 + (size_t)N_DIM * K_DIM);
  float* s_w = s_a + M_DIM;

  quant_x_kernel<<<M_DIM / 4, 256, 0, stream>>>(x, alpha, xq, s_a);
  quant_w_kernel<<<(N_DIM * (size_t)K_DIM) / (256 * 8), 256, 0, stream>>>(Wq, cent, wq8, s_w);

  dim3 grid((M_DIM / BM) * (N_DIM / BN));  // 2048 blocks
  gemm_i8_kernel<<<grid, 256, 0, stream>>>((const unsigned char*)xq, (const unsigned char*)wq8,
                                           out, alpha, s_a, s_w);
}

// Round 4
// 305.415 us; speedup vs baseline: 1.2575x; 1.0857x over previous
//
#include <hip/hip_runtime.h>
#include <math.h>

// Problem dims (fixed by the reference)
#define M_DIM 16384
#define N_DIM 2048
#define K_DIM 2048
#define BM 256
#define BN 128
#define BK 64            // K-tile in BYTES (int8) == one mfma_i32_16x16x64_i8 k-step
#define NT (K_DIM / BK)  // 32 K-tiles

typedef __attribute__((ext_vector_type(4))) int i32x4;    // MFMA i8 A/B (16 int8) and C/D
typedef __attribute__((ext_vector_type(8))) char char8;   // 8B int8 store
typedef __attribute__((ext_vector_type(4))) char char4v;  // 4B int8 store

typedef __attribute__((address_space(1))) const unsigned char global_u8;
typedef __attribute__((address_space(3))) unsigned char lds_u8;

// ---------- pre-pass 1: per-row signed-pow + int8 quantize (one wave per row) ----------
__global__ __launch_bounds__(256) void quant_x_kernel(const float* __restrict__ x,
                                                      const float* __restrict__ alpha,
                                                      char* __restrict__ xq,
                                                      float* __restrict__ s_a) {
  const int wave = threadIdx.x >> 6;
  const int lane = threadIdx.x & 63;
  const int row  = blockIdx.x * 4 + wave;
  const size_t rb = (size_t)row * K_DIM;
  const float a = alpha[0];
  const float4* xp = (const float4*)(x + rb);

  float v[32];
  float m = 0.f;
  if (a == 0.5f) {  // uniform branch; setup uses a = 0.5 exactly
#pragma unroll
    for (int it = 0; it < 8; ++it) {
      float4 t = xp[it * 64 + lane];
      float e[4] = {t.x, t.y, t.z, t.w};
#pragma unroll
      for (int j = 0; j < 4; ++j) {
        float w = copysignf(sqrtf(fabsf(e[j])), e[j]);
        v[it * 4 + j] = w;
        m = fmaxf(m, fabsf(w));
      }
    }
  } else {
#pragma unroll
    for (int it = 0; it < 8; ++it) {
      float4 t = xp[it * 64 + lane];
      float e[4] = {t.x, t.y, t.z, t.w};
#pragma unroll
      for (int j = 0; j < 4; ++j) {
        float w = copysignf(powf(fabsf(e[j]), a), e[j]);
        v[it * 4 + j] = w;
        m = fmaxf(m, fabsf(w));
      }
    }
  }
#pragma unroll
  for (int off = 32; off > 0; off >>= 1) m = fmaxf(m, __shfl_xor(m, off));
  float inv, s;
  if (m > 0.f) { inv = 127.0f / m; s = m * (1.0f / 127.0f); }
  else { inv = 0.f; s = 0.f; }

  char* out = xq + rb;
#pragma unroll
  for (int it = 0; it < 8; ++it) {
    char4v q;
#pragma unroll
    for (int j = 0; j < 4; ++j) {
      int qi = (int)__builtin_rintf(v[it * 4 + j] * inv);
      qi = qi > 127 ? 127 : (qi < -127 ? -127 : qi);
      q[j] = (char)qi;
    }
    *(char4v*)(out + (size_t)(it * 64 + lane) * 4) = q;
  }
  if (lane == 0) s_a[row] = s;
}

// ---------- pre-pass 2: codebook gather -> int8, per-tensor scale (unchanged) ----------
__global__ __launch_bounds__(256) void quant_w_kernel(const int* __restrict__ Wq,
                                                      const float* __restrict__ cent,
                                                      char* __restrict__ wq8,
                                                      float* __restrict__ s_w) {
  __shared__ char cb[16];
  const int tid = threadIdx.x;
  float cmax = 0.f;
#pragma unroll
  for (int j = 0; j < 16; ++j) cmax = fmaxf(cmax, fabsf(cent[j]));
  const float invw = 127.0f / cmax;
  if (tid < 16) cb[tid] = (char)__builtin_rintf(cent[tid] * invw);
  __syncthreads();
  const size_t base = ((size_t)blockIdx.x * 256u + tid) * 8u;
  const int4* qp = (const int4*)(Wq + base);
  int4 q0 = qp[0], q1 = qp[1];
  char8 r;
  r[0] = cb[q0.x]; r[1] = cb[q0.y]; r[2] = cb[q0.z]; r[3] = cb[q0.w];
  r[4] = cb[q1.x]; r[5] = cb[q1.y]; r[6] = cb[q1.z]; r[7] = cb[q1.w];
  *(char8*)(wq8 + base) = r;
  if (blockIdx.x == 0 && tid == 0) s_w[0] = cmax * (1.0f / 127.0f);
}

// ---------- GEMM: 256x128 tile, 8 waves (4m x 2n), 3-buffer ring, counted vmcnt ----------
// Per-wave structure byte-identical to the verified 128^2 kernel (64x64 wave tile,
// acc[4][4], 8 ds_read_b128, swizzle involution phys = logical ^ ((row>>1)&3)).
// Block-level: 512 threads -> one STAGE16 covers 128 rows (8KB), so A=2 + B=1 = 3
// global_load_lds per tile; counted wait is vmcnt(3) (t+2's 3 loads stay in flight).
// Iterations/CU: 1024 blocks x 32 tiles / 256 CU = 128 (was 256) -> half the barrier
// overhead per MFMA. LDS = 3*(16+8)KB = 72KB -> 2 blocks/CU = 16 waves/CU.
#define STAGE16(SRC, DST) \
  __builtin_amdgcn_global_load_lds((global_u8*)(SRC), (lds_u8*)(DST), 16, 0, 0)
#define SBAR() __builtin_amdgcn_sched_barrier(0)

__global__ __launch_bounds__(512, 4) void gemm_i8_kernel(const unsigned char* __restrict__ A,
                                                         const unsigned char* __restrict__ B,
                                                         float* __restrict__ C,
                                                         const float* __restrict__ alpha,
                                                         const float* __restrict__ s_a,
                                                         const float* __restrict__ s_w) {
  __shared__ unsigned char As[3][BM * BK];  // 3 x 16 KiB
  __shared__ unsigned char Bs[3][BN * BK];  // 3 x  8 KiB

  const int tid  = threadIdx.x;
  const int wave = tid >> 6;     // 0..7
  const int lane = tid & 63;
  const int wm   = wave >> 1;    // 0..3 (M band of block tile)
  const int wn   = wave & 1;     // 0..1 (N half)
  const int r    = lane & 15;
  const int quad = lane >> 4;

  // supertile swizzle: 1024 blocks = 64 m-tiles x 16 n-tiles; supertile = 8m x 16n.
  // bid&7 == m-row within supertile == XCD (1024%8==0): per-XCD L2 sees one 512KB
  // A-panel + whole 4MB B.
  const int bid    = blockIdx.x;  // 0..1023
  const int within = bid & 127;
  const int m0 = ((bid >> 7) * 8 + (within & 7)) * BM;
  const int n0 = (within >> 3) * BN;

  // staging: 4 lanes/row (64B rows), 512 threads cover 128 rows per issue.
  // Source pre-swizzled group ^ ((row>>1)&3); LDS dest linear (both-sides rule).
  const int srow = tid >> 2;                       // 0..127
  const int scg  = (tid & 3) ^ ((srow >> 1) & 3);  // involution (row-paired)
  const unsigned char* aSrc = A + (size_t)(m0 + srow) * K_DIM + scg * 16;
  const unsigned char* bSrc = B + (size_t)(n0 + srow) * K_DIM + scg * 16;
  const int dstOff = wave * 1024;                  // wave-uniform base; HW adds lane*16

  // read-side swizzled fragment offsets (matching involution; conflict-free, r3-verified)
  const int swz  = (quad ^ ((r >> 1) & 3)) << 4;
  const int aOff = (wm * 64 + r) * BK + swz;
  const int bOff = (wn * 64 + r) * BK + swz;

  i32x4 acc[4][4];
#pragma unroll
  for (int i = 0; i < 4; ++i)
#pragma unroll
    for (int j = 0; j < 4; ++j) acc[i][j] = i32x4{0, 0, 0, 0};

#define STAGE_TILE(SLOT, K0)                                                     \
  do {                                                                           \
    STAGE16(aSrc + (K0),                       &As[SLOT][dstOff]);               \
    STAGE16(aSrc + (size_t)128 * K_DIM + (K0), &As[SLOT][8192 + dstOff]);        \
    STAGE16(bSrc + (K0),                       &Bs[SLOT][dstOff]);               \
  } while (0)

  // prologue: stage tiles 0 and 1; wait for tile 0 only (tile 1's 3 loads in flight)
  STAGE_TILE(0, 0);
  STAGE_TILE(1, BK);
  asm volatile("s_waitcnt vmcnt(3)" ::: "memory");
  SBAR(); __builtin_amdgcn_s_barrier(); SBAR();

  int buf = 0, pbuf = 2;
  for (int t = 0; t < NT; ++t) {
    if (t + 2 < NT) STAGE_TILE(pbuf, (size_t)(t + 2) * BK);

    const unsigned ap = (unsigned)(size_t)(lds_u8*)&As[buf][aOff];
    const unsigned bp = (unsigned)(size_t)(lds_u8*)&Bs[buf][bOff];
    i32x4 a0, a1, a2, a3, b0, b1, b2, b3;
    asm volatile("ds_read_b128 %0, %4 offset:0\n\t"
                 "ds_read_b128 %1, %4 offset:1024\n\t"
                 "ds_read_b128 %2, %4 offset:2048\n\t"
                 "ds_read_b128 %3, %4 offset:3072"
                 : "=&v"(a0), "=&v"(a1), "=&v"(a2), "=&v"(a3)
                 : "v"(ap));
    asm volatile("ds_read_b128 %0, %4 offset:0\n\t"
                 "ds_read_b128 %1, %4 offset:1024\n\t"
                 "ds_read_b128 %2, %4 offset:2048\n\t"
                 "ds_read_b128 %3, %4 offset:3072"
                 : "=&v"(b0), "=&v"(b1), "=&v"(b2), "=&v"(b3)
                 : "v"(bp));
    asm volatile("s_waitcnt lgkmcnt(0)" ::: "memory");
    SBAR();  // rule #18: pin MFMAs below the wait

    __builtin_amdgcn_s_setprio(1);
    acc[0][0] = __builtin_amdgcn_mfma_i32_16x16x64_i8(a0, b0, acc[0][0], 0, 0, 0);
    acc[0][1] = __builtin_amdgcn_mfma_i32_16x16x64_i8(a0, b1, acc[0][1], 0, 0, 0);
    acc[0][2] = __builtin_amdgcn_mfma_i32_16x16x64_i8(a0, b2, acc[0][2], 0, 0, 0);
    acc[0][3] = __builtin_amdgcn_mfma_i32_16x16x64_i8(a0, b3, acc[0][3], 0, 0, 0);
    acc[1][0] = __builtin_amdgcn_mfma_i32_16x16x64_i8(a1, b0, acc[1][0], 0, 0, 0);
    acc[1][1] = __builtin_amdgcn_mfma_i32_16x16x64_i8(a1, b1, acc[1][1], 0, 0, 0);
    acc[1][2] = __builtin_amdgcn_mfma_i32_16x16x64_i8(a1, b2, acc[1][2], 0, 0, 0);
    acc[1][3] = __builtin_amdgcn_mfma_i32_16x16x64_i8(a1, b3, acc[1][3], 0, 0, 0);
    acc[2][0] = __builtin_amdgcn_mfma_i32_16x16x64_i8(a2, b0, acc[2][0], 0, 0, 0);
    acc[2][1] = __builtin_amdgcn_mfma_i32_16x16x64_i8(a2, b1, acc[2][1], 0, 0, 0);
    acc[2][2] = __builtin_amdgcn_mfma_i32_16x16x64_i8(a2, b2, acc[2][2], 0, 0, 0);
    acc[2][3] = __builtin_amdgcn_mfma_i32_16x16x64_i8(a2, b3, acc[2][3], 0, 0, 0);
    acc[3][0] = __builtin_amdgcn_mfma_i32_16x16x64_i8(a3, b0, acc[3][0], 0, 0, 0);
    acc[3][1] = __builtin_amdgcn_mfma_i32_16x16x64_i8(a3, b1, acc[3][1], 0, 0, 0);
    acc[3][2] = __builtin_amdgcn_mfma_i32_16x16x64_i8(a3, b2, acc[3][2], 0, 0, 0);
    acc[3][3] = __builtin_amdgcn_mfma_i32_16x16x64_i8(a3, b3, acc[3][3], 0, 0, 0);
    __builtin_amdgcn_s_setprio(0);

    // tile end: retire t+1's 3 loads only; t+2's stay in flight across the barrier (T4)
    SBAR();
    if (t < NT - 2) { asm volatile("s_waitcnt vmcnt(3)" ::: "memory"); }
    else            { asm volatile("s_waitcnt vmcnt(0)" ::: "memory"); }
    SBAR(); __builtin_amdgcn_s_barrier(); SBAR();

    buf  = (buf == 2) ? 0 : buf + 1;
    pbuf = (pbuf == 2) ? 0 : pbuf + 1;
  }

  // epilogue: t = s_a[row]*s_w*idot; out = sign(t)*|t|^(1/a); a==0.5 -> t*|t|
  const float a = alpha[0];
  const bool simple = (a == 0.5f);
  const float inv_a = 1.0f / a;
  const float sw = s_w[0];
#pragma unroll
  for (int mf = 0; mf < 4; ++mf) {
    const int gmb = m0 + wm * 64 + mf * 16 + quad * 4;
    float sa[4];
#pragma unroll
    for (int v = 0; v < 4; ++v) sa[v] = s_a[gmb + v] * sw;
#pragma unroll
    for (int nf = 0; nf < 4; ++nf) {
      const int gn = n0 + wn * 64 + nf * 16 + r;
      float* cp = C + (size_t)gmb * N_DIM + gn;
#pragma unroll
      for (int v = 0; v < 4; ++v) {
        float tv = (float)acc[mf][nf][v] * sa[v];
        cp[(size_t)v * N_DIM] = simple ? tv * fabsf(tv)
                                       : copysignf(powf(fabsf(tv), inv_a), tv);
      }
    }
  }
}

extern "C" void kernel_launch(void* const* d_in, const int* in_sizes, int n_in,
                              void* d_out, int out_size, void* d_ws, size_t ws_size,
                              hipStream_t stream) {
  const float* x     = (const float*)d_in[0];  // [16384, 2048] fp32
  const float* cent  = (const float*)d_in[1];  // [16] fp32
  const float* alpha = (const float*)d_in[2];  // [1] fp32
  const int*   Wq    = (const int*)d_in[3];    // [2048, 2048] int32
  float* out = (float*)d_out;                  // [16384, 2048] fp32

  // ws layout: xq int8 [M][K] (32 MiB) | wq8 int8 [N][K] (4 MiB) | s_a [M] f32 | s_w [1] f32
  char*  xq  = (char*)d_ws;
  char*  wq8 = xq + (size_t)M_DIM * K_DIM;
  float* s_a = (float*)(wq8 + (size_t)N_DIM * K_DIM);
  float* s_w = s_a + M_DIM;

  quant_x_kernel<<<M_DIM / 4, 256, 0, stream>>>(x, alpha, xq, s_a);
  quant_w_kernel<<<(N_DIM * (size_t)K_DIM) / (256 * 8), 256, 0, stream>>>(Wq, cent, wq8, s_w);

  dim3 grid((M_DIM / BM) * (N_DIM / BN));  // 1024 blocks
  gemm_i8_kernel<<<grid, 512, 0, stream>>>((const unsigned char*)xq, (const unsigned char*)wq8,
                                           out, alpha, s_a, s_w);
}